// Round 19
// baseline (260.178 us; speedup 1.0000x reference)
//
#include <hip/hip_runtime.h>
#include <hip/hip_bf16.h>
#include <math.h>

#define B_N    1024
#define C_N    64
#define T_N    275
#define S_N    10
#define EMB_N  184
#define PROJ_N 1024
#define CT_N   (C_N * T_N)      // 17600 = k2n K dim (natural eeg layout)
#define TP     288              // padded 275 (9*32)
#define KP2    (C_N * TP)       // 18432 = eT row length (c*288+u)
#define EMBP   192
#define KZN    11               // k2n split-K: 11 * 1600, 1600 = 25*64
#define KCN    1600
#define KZ5    2
#define NT     26               // max m-tiles (subjects padded to 64)

// p_all sectors
#define SEC_WT  0               // 250: subj_W -> Wt[s][t][u] bf16 transposed
#define SEC_E   250             // 192: encW -> eT[192][c*288+u]
#define SEC_1   442             // 48 : W1 -> w1t
#define SEC_2   490             // 256: W2 -> w2t
#define SEC_PB  746             // 64 : pb[c][s][n] = sum_u b_s[u]*encW[(c,u),n]
#define SEC_G   810             // 1  : grouping (msq/stile)
#define SEC_N   811

typedef unsigned short u16;
typedef __attribute__((ext_vector_type(8))) short short8;
typedef __attribute__((ext_vector_type(4))) short short4v;
typedef __attribute__((ext_vector_type(4))) float f32x4;

#define MFMA16(a,b,c) __builtin_amdgcn_mfma_f32_16x16x32_bf16(a, b, c, 0, 0, 0)

__device__ __forceinline__ u16 f2bf(float f) {
    __hip_bfloat16 h = __float2bfloat16(f);     // RNE
    return *reinterpret_cast<u16*>(&h);
}
__device__ __forceinline__ float gelu_exact(float v) {
    return 0.5f * v * (1.0f + erff(v * 0.70710678118654752f));
}
__device__ __forceinline__ void gload16(const void* g, void* lds) {
    __builtin_amdgcn_global_load_lds(
        (const __attribute__((address_space(1))) void*)g,
        (__attribute__((address_space(3))) void*)lds, 16, 0, 0);
}

// ---------------------------------------------------------------------------
// p_all: fused prep
// ---------------------------------------------------------------------------
__global__ __launch_bounds__(256) void p_all(
    const int* __restrict__ sid, const float* __restrict__ W,
    const float* __restrict__ encW, const float* __restrict__ W1,
    const float* __restrict__ W2, const float* __restrict__ subj_b,
    u16* __restrict__ Wt, u16* __restrict__ eT, u16* __restrict__ w1t,
    u16* __restrict__ w2t, float* __restrict__ pb, int* __restrict__ msq,
    int* __restrict__ stile)
{
    __shared__ __align__(16) char smem[16896];
    const int blk = blockIdx.x;
    const int tid = threadIdx.x;

    if (blk < SEC_E) {                      // ---- subj_W -> Wt[s][t:288][u:288]
        float (*tile)[65] = (float(*)[65])smem;
        const int s = blk / 25, local = blk % 25;
        const int u0 = (local / 5) * 64, t0 = (local % 5) * 64;
        for (int l = tid; l < 4096; l += 256) {
            int ii = l >> 6, jj = l & 63;      // ii = u idx, jj = t idx
            int u = u0 + ii, t = t0 + jj;
            float v = (u < T_N && t < T_N)
                ? W[((size_t)s * T_N + u) * T_N + t] : 0.f;
            tile[ii][jj] = v;
        }
        __syncthreads();
        for (int l = tid; l < 4096; l += 256) {
            int jj = l >> 6, ii = l & 63;      // jj = t, ii = u
            int t = t0 + jj, u = u0 + ii;
            if (t < TP && u < TP)
                Wt[((size_t)s * TP + t) * TP + u] = f2bf(tile[ii][jj]);
        }
        return;
    }
    if (blk < SEC_1) {                      // ---- encW -> eT [192][c*288+u]
        float (*tile)[65] = (float(*)[65])smem;
        int local = blk - SEC_E;
        const int c = local / 3;
        const int n0 = (local % 3) * 64;
        for (int u0 = 0; u0 < TP; u0 += 64) {
            int wlen = (TP - u0 < 64) ? (TP - u0) : 64;
            __syncthreads();
            for (int l = tid; l < 4096; l += 256) {
                int i = l >> 6, j = l & 63;
                int u = u0 + i, n = n0 + j;
                float v = 0.f;
                if (u < T_N && n < EMB_N)
                    v = encW[((size_t)c * T_N + u) * EMB_N + n];
                tile[i][j] = v;
            }
            __syncthreads();
            for (int l = tid; l < 4096; l += 256) {
                int j = l >> 6, i = l & 63;
                if (i < wlen)
                    eT[(size_t)(n0 + j) * KP2 + (size_t)c * TP + u0 + i] =
                        f2bf(tile[i][j]);
            }
        }
        return;
    }
    if (blk < SEC_2) {                      // ---- W1 -> w1t [1024][192]
        float (*tile)[65] = (float(*)[65])smem;
        int local = blk - SEC_1;
        const int k0 = (local % 3) * 64, n0 = (local / 3) * 64;
        for (int l = tid; l < 4096; l += 256) {
            int i = l >> 6, j = l & 63;
            float v = (k0 + i < EMB_N) ? W1[(size_t)(k0 + i) * PROJ_N + n0 + j] : 0.f;
            tile[i][j] = v;
        }
        __syncthreads();
        for (int l = tid; l < 4096; l += 256) {
            int j = l >> 6, i = l & 63;
            w1t[(size_t)(n0 + j) * EMBP + k0 + i] = f2bf(tile[i][j]);
        }
        return;
    }
    if (blk < SEC_PB) {                     // ---- W2 -> w2t [1024][1024]
        float (*tile)[65] = (float(*)[65])smem;
        int local = blk - SEC_2;
        const int k0 = (local % 16) * 64, n0 = (local / 16) * 64;
        for (int l = tid; l < 4096; l += 256) {
            int i = l >> 6, j = l & 63;
            tile[i][j] = W2[(size_t)(k0 + i) * PROJ_N + n0 + j];
        }
        __syncthreads();
        for (int l = tid; l < 4096; l += 256) {
            int j = l >> 6, i = l & 63;
            w2t[(size_t)(n0 + j) * PROJ_N + k0 + i] = f2bf(tile[i][j]);
        }
        return;
    }
    if (blk < SEC_G) {                      // ---- pb[c][s][n] ----
        float (*sb)[T_N] = (float(*)[T_N])smem;   // [10][275] = 11000 B
        const int c = blk - SEC_PB;
        for (int i = tid; i < S_N * T_N; i += 256)
            sb[i / T_N][i % T_N] = subj_b[i];
        __syncthreads();
        if (tid < EMB_N) {
            const int n = tid;
            float acc[S_N] = {};
            for (int u = 0; u < T_N; ++u) {
                float ev = encW[((size_t)(c * T_N + u)) * EMB_N + n];
                #pragma unroll
                for (int s = 0; s < S_N; ++s) acc[s] += sb[s][u] * ev;
            }
            #pragma unroll
            for (int s = 0; s < S_N; ++s)
                pb[((size_t)c * S_N + s) * EMBP + n] = acc[s];
        }
        return;
    }
    // ---- grouping: msq[NT*64] (subject-major, padded to 64), stile[NT] ----
    {
        int* sgrp = (int*)smem;                 // [1024]
        int* C    = (int*)(smem + 4096);        // [16][10]
        int* tot  = (int*)(smem + 4096 + 640);  // [10]
        for (int i = tid; i < 1024; i += 256) sgrp[i] = sid[i];
        for (int i = tid; i < NT * 64; i += 256) msq[i] = -1;
        __syncthreads();
        const int w4 = tid >> 6, lane = tid & 63;
        #pragma unroll
        for (int j = 0; j < 4; ++j) {
            int chunk = w4 * 4 + j;
            int sb2 = sgrp[chunk * 64 + lane];
            int myc = 0;
            for (int s = 0; s < S_N; ++s) {
                unsigned long long m = __ballot(sb2 == s);
                if (lane == s) myc = (int)__popcll(m);
            }
            if (lane < S_N) C[chunk * S_N + lane] = myc;
        }
        __syncthreads();
        if (tid < S_N) {
            int a = 0;
            for (int w2 = 0; w2 < 16; ++w2) a += C[w2 * S_N + tid];
            tot[tid] = a;
        }
        __syncthreads();
        #pragma unroll
        for (int rep = 0; rep < 4; ++rep) {
            int b = tid + rep * 256;
            int s = sgrp[b];
            int off64 = 0;
            for (int s2 = 0; s2 < S_N; ++s2)
                if (s2 < s) off64 += ((tot[s2] + 63) >> 6) << 6;
            int chunk = b >> 6;
            int rank = 0;
            for (int w2 = 0; w2 < 16; ++w2)
                if (w2 < chunk) rank += C[w2 * S_N + s];
            for (int i = chunk * 64; i < b; ++i) rank += (sgrp[i] == s) ? 1 : 0;
            msq[off64 + rank] = b;
        }
        __syncthreads();
        if (tid < NT) {
            int acc = 0, val = 0;
            for (int s = 0; s < S_N; ++s) {
                int nt = (tot[s] + 63) >> 6;
                if (tid >= acc && tid < acc + nt) val = s;
                acc += nt;
            }
            stile[tid] = val;
        }
    }
}

// ---------------------------------------------------------------------------
// prepM: M[sl][n:192][c*275+t] = sum_u Wt[s][t][u] * eT[n][c*288+u]  (bf16)
// grid 3201: blk<3200 GEMM (s = blk/320, c = (blk%320)/5, tt = blk%5);
// blk==3200 & phase0: bias2[s][n] = enc_b[n] + sum_c pb[c][s][n].
// 256 thr = 4 waves, wave = 48 n x 64 t. a-op = eT rows n (staged, dbuf);
// b-op = Wt rows t (direct, L2). K = 288 = 9 x 32.
// ---------------------------------------------------------------------------
__global__ __launch_bounds__(256) void prepM(
    const u16* __restrict__ eT, const u16* __restrict__ Wt,
    const float* __restrict__ pb, const float* __restrict__ enc_b,
    float* __restrict__ bias2, u16* __restrict__ M, int phase)
{
    const int blk = blockIdx.x;
    const int tid = threadIdx.x;
    if (blk == 3200) {
        if (phase == 0) {
            for (int o = tid; o < S_N * EMBP; o += 256) {
                int s = o / EMBP, n = o % EMBP;
                float v = 0.f;
                if (n < EMB_N) {
                    v = enc_b[n];
                    for (int c = 0; c < C_N; ++c)
                        v += pb[((size_t)c * S_N + s) * EMBP + n];
                }
                bias2[s * EMBP + n] = v;
            }
        }
        return;
    }
    const int s = blk / 320, rem = blk % 320;
    const int c = rem / 5, tt = rem % 5;
    if (phase == 0 ? (s >= 5) : (s < 5)) return;
    const int sl = s - phase * 5;
    const int t0 = tt * 64;

    __shared__ __align__(16) u16 Ea[2][192 * 32];   // 2 x 12 KB
    const int w = tid >> 6, lane = tid & 63;
    const int lrow = lane & 15, lk = lane >> 4;
    const u16* Wr = Wt + (size_t)s * TP * TP;

    #define PM_STAGE(st, ks)                                                   \
        _Pragma("unroll")                                                      \
        for (int p = 0; p < 3; ++p) {                                          \
            int L = tid + p * 256;                                             \
            int row = L >> 2, q = L & 3;                                       \
            gload16(eT + (size_t)row * KP2 + c * TP + (ks) * 32 +              \
                        ((q ^ (row & 3)) << 3),                                \
                    &Ea[st][L * 8]);                                           \
        }
    #define PM_BLOAD(ks, dst)                                                  \
        _Pragma("unroll")                                                      \
        for (int ct = 0; ct < 4; ++ct)                                         \
            dst[ct] = *reinterpret_cast<const short8*>(                        \
                Wr + (size_t)(t0 + ct * 16 + lrow) * TP + (ks) * 32 + 8 * lk);

    f32x4 acc[3][4] = {};
    short8 bf[4], bn[4];

    PM_STAGE(0, 0);
    PM_BLOAD(0, bf);
    __syncthreads();

    for (int ks = 0; ks < 9; ++ks) {
        const int st = ks & 1;
        if (ks < 8) {
            PM_STAGE(st ^ 1, ks + 1);
            PM_BLOAD(ks + 1, bn);
        }
        #pragma unroll
        for (int rt = 0; rt < 3; ++rt) {
            int n = w * 48 + rt * 16 + lrow;
            short8 af = *reinterpret_cast<const short8*>(
                &Ea[st][(n * 4 + (lk ^ (n & 3))) * 8]);
            #pragma unroll
            for (int ct = 0; ct < 4; ++ct)
                acc[rt][ct] = MFMA16(af, bf[ct], acc[rt][ct]);
        }
        __syncthreads();
        #pragma unroll
        for (int ct = 0; ct < 4; ++ct) bf[ct] = bn[ct];
    }

    #pragma unroll
    for (int rt = 0; rt < 3; ++rt)
        #pragma unroll
        for (int ct = 0; ct < 4; ++ct) {
            int t = t0 + ct * 16 + lrow;
            if (t < T_N) {
                #pragma unroll
                for (int r = 0; r < 4; ++r) {
                    int n = w * 48 + rt * 16 + 4 * lk + r;
                    M[(size_t)(sl * EMBP + n) * CT_N + (size_t)c * T_N + t] =
                        f2bf(acc[rt][ct][r]);
                }
            }
        }
    #undef PM_STAGE
    #undef PM_BLOAD
}

// ---------------------------------------------------------------------------
// k2n: part[kz][slot][n] = sum_{k chunk} eeg[b(slot)][k] * M[sl][n][k]
// grid NT*KZN = 286. A = eeg f32 (natural layout, aligned), staged to LDS,
// converted at fragment read. B = M rows n, direct. K-chunk 1600 = 25 x 64.
// ---------------------------------------------------------------------------
__global__ __launch_bounds__(256) void k2n(
    const float* __restrict__ eeg, const u16* __restrict__ M,
    const int* __restrict__ msq, const int* __restrict__ stile,
    float* __restrict__ part, int phase)
{
    __shared__ __align__(16) float Ea[2][64 * 64];   // 2 x 16 KB
    const int B = blockIdx.x;
    const int tile = B / KZN, kz = B % KZN;
    const int s = stile[tile];
    if (phase == 0 ? (s >= 5) : (s < 5)) return;
    const int sl = s - phase * 5;
    const int kbase = kz * KCN;
    const int tid = threadIdx.x;
    const int w = tid >> 6, lane = tid & 63;
    const int lrow = lane & 15, lk = lane >> 4;

    // per-thread A row pointers (4 stage chunks)
    const float* ap[4];
    #pragma unroll
    for (int p = 0; p < 4; ++p) {
        int r_ = (tid >> 4) + p * 16;
        int q_ = tid & 15;
        int bb = msq[tile * 64 + r_]; if (bb < 0) bb = 0;
        ap[p] = eeg + (size_t)bb * CT_N + ((q_ ^ (r_ & 7)) << 2);
    }
    const u16* Mb = M + (size_t)sl * EMBP * CT_N;

    #define KN_STAGE(st, step)                                                 \
        _Pragma("unroll")                                                      \
        for (int p = 0; p < 4; ++p)                                            \
            gload16(ap[p] + kbase + (step) * 64, &Ea[st][(tid + p * 256) * 4]);
    #define KN_BLOAD(step, dst)                                                \
        _Pragma("unroll")                                                      \
        for (int ct = 0; ct < 3; ++ct)                                         \
            _Pragma("unroll")                                                  \
            for (int ki = 0; ki < 2; ++ki)                                     \
                dst[ct][ki] = *reinterpret_cast<const short8*>(                \
                    Mb + (size_t)(w * 48 + ct * 16 + lrow) * CT_N + kbase +    \
                    (step) * 64 + ki * 32 + 8 * lk);

    f32x4 acc[4][3] = {};
    short8 bf[3][2], bn[3][2];

    KN_STAGE(0, 0);
    KN_BLOAD(0, bf);
    __syncthreads();

    for (int step = 0; step < 25; ++step) {
        const int st = step & 1;
        if (step < 24) {
            KN_STAGE(st ^ 1, step + 1);
            KN_BLOAD(step + 1, bn);
        }
        #pragma unroll
        for (int ki = 0; ki < 2; ++ki)
            #pragma unroll
            for (int rt = 0; rt < 4; ++rt) {
                int m = 16 * rt + lrow;
                int c0 = ki * 8 + lk * 2;
                int s7 = m & 7;
                float4 f0 = *reinterpret_cast<const float4*>(
                    &Ea[st][m * 64 + ((c0 ^ s7) << 2)]);
                float4 f1 = *reinterpret_cast<const float4*>(
                    &Ea[st][m * 64 + (((c0 + 1) ^ s7) << 2)]);
                short8 af;
                af[0] = (short)f2bf(f0.x); af[1] = (short)f2bf(f0.y);
                af[2] = (short)f2bf(f0.z); af[3] = (short)f2bf(f0.w);
                af[4] = (short)f2bf(f1.x); af[5] = (short)f2bf(f1.y);
                af[6] = (short)f2bf(f1.z); af[7] = (short)f2bf(f1.w);
                #pragma unroll
                for (int ct = 0; ct < 3; ++ct)
                    acc[rt][ct] = MFMA16(af, bf[ct][ki], acc[rt][ct]);
            }
        __syncthreads();
        #pragma unroll
        for (int ct = 0; ct < 3; ++ct)
            #pragma unroll
            for (int ki = 0; ki < 2; ++ki) bf[ct][ki] = bn[ct][ki];
    }

    #pragma unroll
    for (int rt = 0; rt < 4; ++rt)
        #pragma unroll
        for (int ct = 0; ct < 3; ++ct) {
            int n = w * 48 + ct * 16 + lrow;
            #pragma unroll
            for (int r = 0; r < 4; ++r) {
                int m = 16 * rt + 4 * lk + r;
                part[((size_t)kz * (NT * 64) + tile * 64 + m) * EMBP + n] =
                    acc[rt][ct][r];
            }
        }
    #undef KN_STAGE
    #undef KN_BLOAD
}

// ---------------------------------------------------------------------------
// k3n: hb[b][n] = bf16(bias2[s][n] + sum_kz part[kz][slot][n]); n>=184 -> 0
// ---------------------------------------------------------------------------
__global__ __launch_bounds__(256) void k3n(
    const float* __restrict__ part, const float* __restrict__ bias2,
    const int* __restrict__ msq, const int* __restrict__ stile,
    u16* __restrict__ hb)
{
    int idx = blockIdx.x * 256 + threadIdx.x;
    if (idx >= NT * 64 * EMBP) return;
    int slot = idx / EMBP, n = idx % EMBP;
    int b = msq[slot];
    if (b < 0) return;
    float v = 0.f;
    if (n < EMB_N) {
        v = bias2[stile[slot >> 6] * EMBP + n];
        #pragma unroll
        for (int kz = 0; kz < KZN; ++kz)
            v += part[((size_t)kz * (NT * 64) + slot) * EMBP + n];
    }
    hb[(size_t)b * EMBP + n] = f2bf(v);
}

// ---------------------------------------------------------------------------
// k4: h1 = hb @ W1 + b1 (K=192); g = bf16(gelu(h1))   (grid 256, XCD swizzle)
// ---------------------------------------------------------------------------
__global__ __launch_bounds__(256) void k4_mfma(
    const u16* __restrict__ hb, const u16* __restrict__ w1t,
    const float* __restrict__ b1, float* __restrict__ h1, u16* __restrict__ g)
{
    __shared__ __align__(16) u16 Ab[64 * EMBP];
    __shared__ __align__(16) u16 Bb[64 * EMBP];
    const int B = blockIdx.x;
    const int work = (B & 7) * 32 + (B >> 3);
    const int m0 = (work >> 4) * 64, n0 = (work & 15) * 64;
    const int tid = threadIdx.x;
    const int w = tid >> 6, lane = tid & 63;
    const int wr = w >> 1, wc = w & 1;
    const int lrow = lane & 15, lk = lane >> 4;

    #pragma unroll
    for (int i = 0; i < 6; ++i) {
        int L = tid + i * 256;
        int row = L / 24, qp = L % 24;
        int ql = qp ^ (row & 7);
        gload16(hb  + (size_t)(m0 + row) * EMBP + ql * 8, &Ab[(size_t)L * 8]);
        gload16(w1t + (size_t)(n0 + row) * EMBP + ql * 8, &Bb[(size_t)L * 8]);
    }
    __syncthreads();

    f32x4 acc[2][2] = {};
    #pragma unroll
    for (int ks = 0; ks < 6; ++ks) {
        #pragma unroll
        for (int rt = 0; rt < 2; ++rt) {
            int c = 32 * wr + 16 * rt + lrow;
            short8 af = *reinterpret_cast<const short8*>(
                &Ab[c * EMBP + (((4 * ks + lk) ^ (c & 7)) * 8)]);
            #pragma unroll
            for (int ct = 0; ct < 2; ++ct) {
                int nl = 32 * wc + 16 * ct + lrow;
                short8 bfv = *reinterpret_cast<const short8*>(
                    &Bb[nl * EMBP + (((4 * ks + lk) ^ (nl & 7)) * 8)]);
                acc[rt][ct] = MFMA16(af, bfv, acc[rt][ct]);
            }
        }
    }
    #pragma unroll
    for (int rt = 0; rt < 2; ++rt)
        #pragma unroll
        for (int ct = 0; ct < 2; ++ct) {
            int n = n0 + 32 * wc + 16 * ct + lrow;
            #pragma unroll
            for (int r = 0; r < 4; ++r) {
                int m = m0 + 32 * wr + 16 * rt + 4 * lk + r;
                float v = acc[rt][ct][r] + b1[n];
                size_t o = (size_t)m * PROJ_N + n;
                h1[o] = v;
                g[o] = f2bf(gelu_exact(v));
            }
        }
}

// ---------------------------------------------------------------------------
// k5: part2[kz] = g @ W2 chunk (K=512 each), BK=64, dbuf (grid 512, swizzle)
// ---------------------------------------------------------------------------
__global__ __launch_bounds__(256) void k5_mfma(
    const u16* __restrict__ g, const u16* __restrict__ w2t,
    float* __restrict__ part2)
{
    __shared__ __align__(16) u16 Ab[2][64 * 64];
    __shared__ __align__(16) u16 Bb[2][64 * 64];
    const int B = blockIdx.x;
    const int work = (B & 7) * 64 + (B >> 3);
    const int m0 = (work >> 5) * 64;
    const int rem = work & 31;
    const int n0 = (rem >> 1) * 64;
    const int kz = rem & 1;
    const int kbase = kz * (PROJ_N / KZ5);
    const int tid = threadIdx.x;
    const int w = tid >> 6, lane = tid & 63;
    const int wr = w >> 1, wc = w & 1;
    const int lrow = lane & 15, lk = lane >> 4;

    const int r0 = tid >> 3, q0 = tid & 7;
    const int r1 = (tid + 256) >> 3;
    const u16* a0 = g + (size_t)(m0 + r0) * PROJ_N + (q0 ^ (r0 & 7)) * 8;
    const u16* a1 = g + (size_t)(m0 + r1) * PROJ_N + (q0 ^ (r1 & 7)) * 8;
    const u16* b0 = w2t + (size_t)(n0 + r0) * PROJ_N + (q0 ^ (r0 & 7)) * 8;
    const u16* b1p = w2t + (size_t)(n0 + r1) * PROJ_N + (q0 ^ (r1 & 7)) * 8;

    f32x4 acc[2][2] = {};
    int buf = 0;
    gload16(a0 + kbase, &Ab[0][(size_t)(w * 64) * 8]);
    gload16(a1 + kbase, &Ab[0][(size_t)(w * 64 + 256) * 8]);
    gload16(b0 + kbase, &Bb[0][(size_t)(w * 64) * 8]);
    gload16(b1p + kbase, &Bb[0][(size_t)(w * 64 + 256) * 8]);
    __syncthreads();

    for (int step = 0; step < 8; ++step) {
        if (step < 7) {
            int k0 = kbase + (step + 1) * 64;
            gload16(a0 + k0, &Ab[buf ^ 1][(size_t)(w * 64) * 8]);
            gload16(a1 + k0, &Ab[buf ^ 1][(size_t)(w * 64 + 256) * 8]);
            gload16(b0 + k0, &Bb[buf ^ 1][(size_t)(w * 64) * 8]);
            gload16(b1p + k0, &Bb[buf ^ 1][(size_t)(w * 64 + 256) * 8]);
        }
        #pragma unroll
        for (int ki = 0; ki < 2; ++ki) {
            #pragma unroll
            for (int rt = 0; rt < 2; ++rt) {
                int c = 32 * wr + 16 * rt + lrow;
                short8 af = *reinterpret_cast<const short8*>(
                    &Ab[buf][c * 64 + (((lk + 4 * ki) ^ (c & 7)) * 8)]);
                #pragma unroll
                for (int ct = 0; ct < 2; ++ct) {
                    int nl = 32 * wc + 16 * ct + lrow;
                    short8 bfv = *reinterpret_cast<const short8*>(
                        &Bb[buf][nl * 64 + (((lk + 4 * ki) ^ (nl & 7)) * 8)]);
                    acc[rt][ct] = MFMA16(af, bfv, acc[rt][ct]);
                }
            }
        }
        __syncthreads();
        buf ^= 1;
    }
    #pragma unroll
    for (int rt = 0; rt < 2; ++rt)
        #pragma unroll
        for (int ct = 0; ct < 2; ++ct) {
            int n = n0 + 32 * wc + 16 * ct + lrow;
            #pragma unroll
            for (int r = 0; r < 4; ++r) {
                int m = m0 + 32 * wr + 16 * rt + 4 * lk + r;
                part2[(size_t)kz * B_N * PROJ_N + (size_t)m * PROJ_N + n] = acc[rt][ct][r];
            }
        }
}

// ---------------------------------------------------------------------------
// k5r_ln: hr = h1 + (part2[0]+part2[1]+b2); out = LN(hr)*gamma+beta
// ---------------------------------------------------------------------------
__global__ __launch_bounds__(256) void k5r_ln(
    const float* __restrict__ part2, const float* __restrict__ h1,
    const float* __restrict__ b2, const float* __restrict__ gamma,
    const float* __restrict__ beta, float* __restrict__ out)
{
    const int m = blockIdx.x;
    const int tid = threadIdx.x;
    const float4* h4 = reinterpret_cast<const float4*>(h1 + (size_t)m * PROJ_N);
    const float4* p0 = reinterpret_cast<const float4*>(part2 + (size_t)m * PROJ_N);
    const float4* p1 = reinterpret_cast<const float4*>(part2 + (size_t)(B_N + m) * PROJ_N);
    const float4* b4 = reinterpret_cast<const float4*>(b2);
    float4 va = h4[tid], vb = p0[tid], vc = p1[tid], vd = b4[tid];
    float v[4] = { va.x + vb.x + vc.x + vd.x, va.y + vb.y + vc.y + vd.y,
                   va.z + vb.z + vc.z + vd.z, va.w + vb.w + vc.w + vd.w };
    float s = 0.f, sq = 0.f;
    #pragma unroll
    for (int i = 0; i < 4; ++i) { s += v[i]; sq += v[i] * v[i]; }
    #pragma unroll
    for (int off = 32; off > 0; off >>= 1) {
        s  += __shfl_down(s, off);
        sq += __shfl_down(sq, off);
    }
    __shared__ float ss[4], ssq[4];
    int wid = tid >> 6, lane = tid & 63;
    if (lane == 0) { ss[wid] = s; ssq[wid] = sq; }
    __syncthreads();
    if (tid == 0) {
        float a = 0.f, bsum = 0.f;
        #pragma unroll
        for (int q = 0; q < 4; ++q) { a += ss[q]; bsum += ssq[q]; }
        ss[0] = a; ssq[0] = bsum;
    }
    __syncthreads();
    float mu  = ss[0] * (1.0f / PROJ_N);
    float var = ssq[0] * (1.0f / PROJ_N) - mu * mu;
    float rs  = rsqrtf(var + 1e-5f);
    const float4 g4 = reinterpret_cast<const float4*>(gamma)[tid];
    const float4 be4 = reinterpret_cast<const float4*>(beta)[tid];
    float gg[4] = { g4.x, g4.y, g4.z, g4.w };
    float bb[4] = { be4.x, be4.y, be4.z, be4.w };
    float4 o4;
    float* op = reinterpret_cast<float*>(&o4);
    #pragma unroll
    for (int i = 0; i < 4; ++i) op[i] = (v[i] - mu) * rs * gg[i] + bb[i];
    reinterpret_cast<float4*>(out + (size_t)m * PROJ_N)[tid] = o4;
}

// ---------------------------------------------------------------------------
extern "C" void kernel_launch(void* const* d_in, const int* in_sizes, int n_in,
                              void* d_out, int out_size, void* d_ws, size_t ws_size,
                              hipStream_t stream)
{
    const float* eeg    = (const float*)d_in[0];
    const int*   sid    = (const int*)  d_in[1];
    const float* subj_W = (const float*)d_in[2];
    const float* subj_b = (const float*)d_in[3];
    const float* enc_W  = (const float*)d_in[4];
    const float* enc_b  = (const float*)d_in[5];
    const float* W1     = (const float*)d_in[6];
    const float* b1     = (const float*)d_in[7];
    const float* W2     = (const float*)d_in[8];
    const float* b2     = (const float*)d_in[9];
    const float* gamma  = (const float*)d_in[10];
    const float* beta   = (const float*)d_in[11];
    float* out = (float*)d_out;

    char* w = (char*)d_ws;
    u16*   Wt    = (u16*)(w);                    //  1,658,880 (10*288*288*2)
    u16*   eT    = (u16*)(w + 1658880);          //  7,077,888 (192*18432*2)
    u16*   w1t   = (u16*)(w + 8736768);          //    393,216
    u16*   w2t   = (u16*)(w + 9129984);          //  2,097,152
    u16*   hb    = (u16*)(w + 11227136);         //    393,216
    float* h1    = (float*)(w + 11620352);       //  4,194,304
    u16*   g     = (u16*)(w + 15814656);         //  2,097,152
    float* pb    = (float*)(w + 17911808);       //    491,520 (64*10*192*4)
    float* bias2 = (float*)(w + 18403328);       //      7,680
    int*   msq   = (int*)(w + 18411008);         //      6,656
    int*   stile = (int*)(w + 18417664);         //        128
    u16*   M     = (u16*)(w + 18417792);         // 33,792,000 (5*192*17600*2)
    float* part  = (float*)(w + 52209792);       // 14,057,472 (11*1664*192*4)
    float* part2 = (float*)(w + 66267264);       //  8,388,608 -> end 74,655,872

    p_all<<<dim3(SEC_N), 256, 0, stream>>>(sid, subj_W, enc_W, W1, W2, subj_b,
                                           Wt, eT, w1t, w2t, pb, msq, stile);
    prepM<<<dim3(3201), 256, 0, stream>>>(eT, Wt, pb, enc_b, bias2, M, 0);
    k2n  <<<dim3(NT * KZN), 256, 0, stream>>>(eeg, M, msq, stile, part, 0);
    prepM<<<dim3(3201), 256, 0, stream>>>(eT, Wt, pb, enc_b, bias2, M, 1);
    k2n  <<<dim3(NT * KZN), 256, 0, stream>>>(eeg, M, msq, stile, part, 1);
    k3n  <<<dim3((NT * 64 * EMBP + 255) / 256), 256, 0, stream>>>(part, bias2,
                                                                  msq, stile, hb);
    k4_mfma<<<dim3(256), 256, 0, stream>>>(hb, w1t, b1, h1, g);
    k5_mfma<<<dim3(512), 256, 0, stream>>>(g, w2t, part2);
    k5r_ln <<<dim3(B_N), 256, 0, stream>>>(part2, h1, b2, gamma, beta, out);
}

// Round 20
// 118.334 us; speedup vs baseline: 2.1987x; 2.1987x over previous
//
#include <hip/hip_runtime.h>
#include <hip/hip_bf16.h>
#include <math.h>

#define B_N    1024
#define C_N    64
#define T_N    275
#define S_N    10
#define EMB_N  184
#define PROJ_N 1024
#define CT_N   (C_N * T_N)      // 17600
#define TP     288              // padded T (9*32): K extent of k1 and u extent
#define KP2    (C_N * TP)       // 18432 = k2 K dim (c*288+u)
#define EMBP   192
#define KZ2    16
#define KC2    (KP2 / KZ2)      // 1152
#define KZ5    2
#define GMAX   264

// p_all sector starts
#define SEC_W   0               // 810 blocks: subj_W -> bf16 padded
#define SEC_E   810             // 192 blocks: encW transpose
#define SEC_1   1002            // 48  blocks: W1 transpose
#define SEC_2   1050            // 256 blocks: W2 transpose
#define SEC_G   1306            // 1 block: grouping + bias pad
#define SEC_N   1307

typedef unsigned short u16;
typedef __attribute__((ext_vector_type(8))) short short8;
typedef __attribute__((ext_vector_type(4))) short short4v;
typedef __attribute__((ext_vector_type(4))) float f32x4;

#define MFMA16(a,b,c) __builtin_amdgcn_mfma_f32_16x16x32_bf16(a, b, c, 0, 0, 0)

__device__ __forceinline__ u16 f2bf(float f) {
    __hip_bfloat16 h = __float2bfloat16(f);     // RNE
    return *reinterpret_cast<u16*>(&h);
}
__device__ __forceinline__ float gelu_exact(float v) {
    return 0.5f * v * (1.0f + erff(v * 0.70710678118654752f));
}
__device__ __forceinline__ void gload16(const void* g, void* lds) {
    __builtin_amdgcn_global_load_lds(
        (const __attribute__((address_space(1))) void*)g,
        (__attribute__((address_space(3))) void*)lds, 16, 0, 0);
}

// ---------------------------------------------------------------------------
// p_all: fused prep
// ---------------------------------------------------------------------------
__global__ __launch_bounds__(256) void p_all(
    const int* __restrict__ sid, const float* __restrict__ W,
    const float* __restrict__ encW, const float* __restrict__ W1,
    const float* __restrict__ W2, const float* __restrict__ subj_b,
    u16* __restrict__ Wb, u16* __restrict__ eT, u16* __restrict__ w1t,
    u16* __restrict__ w2t, int* __restrict__ bsq, float* __restrict__ sbp)
{
    __shared__ char smem[16640];
    const int blk = blockIdx.x;
    const int tid = threadIdx.x;

    if (blk < SEC_E) {                      // ---- subj_W -> Wb [10][288u][288t]
        int idx4 = blk * 256 + tid;
        if (idx4 >= S_N * TP * TP / 4) return;
        int o = idx4 * 4;
        int row = o / TP, t = o - row * TP;   // row = s*288+u
        int s = row / TP, u = row - s * TP;
        short4v pk;
        #pragma unroll
        for (int e = 0; e < 4; ++e) {
            float v = (u < T_N && t + e < T_N)
                ? W[((size_t)s * T_N + u) * T_N + t + e] : 0.f;
            pk[e] = (short)f2bf(v);
        }
        *reinterpret_cast<short4v*>(Wb + o) = pk;
        return;
    }
    if (blk < SEC_1) {                      // ---- encW -> eT [192][c*288+u]
        float (*tile)[65] = (float(*)[65])smem;
        int local = blk - SEC_E;
        const int c = local / 3;
        const int n0 = (local % 3) * 64;
        for (int u0 = 0; u0 < TP; u0 += 64) {
            int wlen = (TP - u0 < 64) ? (TP - u0) : 64;
            __syncthreads();
            for (int l = tid; l < 4096; l += 256) {
                int i = l >> 6, j = l & 63;
                int u = u0 + i, n = n0 + j;
                float v = 0.f;
                if (u < T_N && n < EMB_N)
                    v = encW[((size_t)c * T_N + u) * EMB_N + n];
                tile[i][j] = v;
            }
            __syncthreads();
            for (int l = tid; l < 4096; l += 256) {
                int j = l >> 6, i = l & 63;
                if (i < wlen)
                    eT[(size_t)(n0 + j) * KP2 + (size_t)c * TP + u0 + i] =
                        f2bf(tile[i][j]);
            }
        }
        return;
    }
    if (blk < SEC_2) {                      // ---- W1 -> w1t [1024][192]
        float (*tile)[65] = (float(*)[65])smem;
        int local = blk - SEC_1;
        const int k0 = (local % 3) * 64, n0 = (local / 3) * 64;
        for (int l = tid; l < 4096; l += 256) {
            int i = l >> 6, j = l & 63;
            float v = (k0 + i < EMB_N) ? W1[(size_t)(k0 + i) * PROJ_N + n0 + j] : 0.f;
            tile[i][j] = v;
        }
        __syncthreads();
        for (int l = tid; l < 4096; l += 256) {
            int j = l >> 6, i = l & 63;
            w1t[(size_t)(n0 + j) * EMBP + k0 + i] = f2bf(tile[i][j]);
        }
        return;
    }
    if (blk < SEC_G) {                      // ---- W2 -> w2t [1024][1024]
        float (*tile)[65] = (float(*)[65])smem;
        int local = blk - SEC_2;
        const int k0 = (local % 16) * 64, n0 = (local / 16) * 64;
        for (int l = tid; l < 4096; l += 256) {
            int i = l >> 6, j = l & 63;
            tile[i][j] = W2[(size_t)(k0 + i) * PROJ_N + n0 + j];
        }
        __syncthreads();
        for (int l = tid; l < 4096; l += 256) {
            int j = l >> 6, i = l & 63;
            w2t[(size_t)(n0 + j) * PROJ_N + k0 + i] = f2bf(tile[i][j]);
        }
        return;
    }
    // ---- grouping + bias pad ----
    {
        for (int i = tid; i < S_N * TP; i += 256) {
            int s = i / TP, u = i - s * TP;
            sbp[i] = (u < T_N) ? subj_b[s * T_N + u] : 0.f;
        }
        int* sgrp = (int*)smem;                 // [1024]
        int* C    = (int*)(smem + 4096);        // [16][10]
        int* tot  = (int*)(smem + 4096 + 640);  // [10]
        for (int i = tid; i < 1024; i += 256) sgrp[i] = sid[i];
        for (int i = tid; i < 4 * GMAX; i += 256) bsq[i] = -1;
        __syncthreads();
        const int w4 = tid >> 6, lane = tid & 63;
        #pragma unroll
        for (int j = 0; j < 4; ++j) {
            int chunk = w4 * 4 + j;
            int sb = sgrp[chunk * 64 + lane];
            int myc = 0;
            for (int s = 0; s < S_N; ++s) {
                unsigned long long m = __ballot(sb == s);
                if (lane == s) myc = (int)__popcll(m);
            }
            if (lane < S_N) C[chunk * S_N + lane] = myc;
        }
        __syncthreads();
        if (tid < S_N) {
            int a = 0;
            for (int w2 = 0; w2 < 16; ++w2) a += C[w2 * S_N + tid];
            tot[tid] = a;
        }
        __syncthreads();
        #pragma unroll
        for (int rep = 0; rep < 4; ++rep) {
            int b = tid + rep * 256;
            int s = sgrp[b];
            int off = 0;
            for (int s2 = 0; s2 < S_N; ++s2)
                if (s2 < s) off += (tot[s2] + 3) & ~3;
            int chunk = b >> 6;
            int rank = 0;
            for (int w2 = 0; w2 < 16; ++w2)
                if (w2 < chunk) rank += C[w2 * S_N + s];
            for (int i = chunk * 64; i < b; ++i) rank += (sgrp[i] == s) ? 1 : 0;
            bsq[off + rank] = b;
        }
    }
}

// ---------------------------------------------------------------------------
// k1p: k1h + triple-buffered W stage + counted vmcnt + raw s_barrier.
// grid (GMAX, 2): y = c-half. 512 thr = 8 waves = 4 b's x 2 u-halves.
// ---------------------------------------------------------------------------
__global__ __launch_bounds__(512) void k1p(
    const float* __restrict__ eeg, const int* __restrict__ sid,
    const u16* __restrict__ Wb, const float* __restrict__ sbp,
    const int* __restrict__ bsq, u16* __restrict__ xb)
{
    __shared__ __align__(16) u16 Ws[3][TP * 32];     // 3 x 18 KB = 54 KB
    __shared__ __align__(16) u16 Es[2][128 * 40];    // 2 x 10 KB = 20 KB
    const int g = blockIdx.x;
    const int b0 = bsq[g * 4];
    if (b0 < 0) return;
    const int ch = blockIdx.y;
    const int s = sid[b0];
    const int tid = threadIdx.x;
    const int w = tid >> 6, lane = tid & 63;
    const int bi = w >> 1, uh = w & 1;
    const int lrow = lane & 15, lk = lane >> 4;
    const int b = bsq[g * 4 + bi];
    const u16* Wr = Wb + (size_t)s * TP * TP;

    const int srow = tid >> 2;           // 0..127
    const int quarter = tid & 3;
    const int bt = srow >> 5, cl = srow & 31;
    int bstage = bsq[g * 4 + bt]; if (bstage < 0) bstage = b0;
    const float* esrc = eeg + (size_t)bstage * CT_N + (ch * 32 + cl) * T_N;

    #define K1_WSTAGE(bufi, ks)                                                \
        for (int l = tid; l < TP * 4; l += 512) {                              \
            int u_ = l >> 2, q_ = l & 3;                                       \
            gload16(Wr + (size_t)u_ * TP + (ks) * 32 + ((q_ ^ ((u_ >> 1) & 3)) << 3), \
                    &Ws[bufi][l * 8]);                                         \
        }
    #define K1_ELOAD(ks, v)                                                    \
        {   int t0_ = (ks) * 32 + quarter * 8;                                 \
            if ((ks) < 8) {                                                    \
                _Pragma("unroll")                                              \
                for (int e = 0; e < 8; ++e) v[e] = esrc[t0_ + e];              \
            } else {                                                           \
                _Pragma("unroll")                                              \
                for (int e = 0; e < 8; ++e)                                    \
                    v[e] = (t0_ + e < T_N) ? esrc[t0_ + e] : 0.f;              \
            }                                                                  \
        }
    #define K1_EWRITE(st, v)                                                   \
        {   short8 pk_;                                                        \
            _Pragma("unroll")                                                  \
            for (int e = 0; e < 8; ++e) pk_[e] = (short)f2bf(v[e]);            \
            *reinterpret_cast<short8*>(&Es[st][srow * 40 + quarter * 8]) = pk_;\
        }
    #define K1_WAITN()                                                         \
        {   if (w < 2) asm volatile("s_waitcnt vmcnt(3) lgkmcnt(0)" ::: "memory"); \
            else       asm volatile("s_waitcnt vmcnt(2) lgkmcnt(0)" ::: "memory"); }

    f32x4 acc[9][2] = {};
    float ev[8], evn[8];

    K1_ELOAD(0, ev);
    K1_WSTAGE(0, 0);
    K1_WSTAGE(1, 1);
    K1_EWRITE(0, ev);
    K1_WAITN();
    __builtin_amdgcn_s_barrier();

    for (int ks = 0; ks < 9; ++ks) {
        const int wb = ks % 3, eb = ks & 1;
        if (ks < 8) K1_ELOAD(ks + 1, evn);
        if (ks < 7) K1_WSTAGE((ks + 2) % 3, ks + 2);

        short8 ef[2];
        #pragma unroll
        for (int cf = 0; cf < 2; ++cf)
            ef[cf] = *reinterpret_cast<const short8*>(
                &Es[eb][(bi * 32 + cf * 16 + lrow) * 40 + lk * 8]);
        __builtin_amdgcn_s_setprio(1);
        #pragma unroll
        for (int uf = 0; uf < 9; ++uf) {
            int u = uh * 144 + uf * 16 + lrow;
            int chunk = u * 4 + (lk ^ ((u >> 1) & 3));
            short8 av = *reinterpret_cast<const short8*>(&Ws[wb][chunk * 8]);
            acc[uf][0] = MFMA16(av, ef[0], acc[uf][0]);
            acc[uf][1] = MFMA16(av, ef[1], acc[uf][1]);
        }
        __builtin_amdgcn_s_setprio(0);

        if (ks < 8) K1_EWRITE(eb ^ 1, evn);
        if (ks < 7) { K1_WAITN(); }
        else asm volatile("s_waitcnt vmcnt(0) lgkmcnt(0)" ::: "memory");
        if (ks < 8) __builtin_amdgcn_s_barrier();
    }

    if (b < 0) return;
    u16* xrow = xb + (size_t)b * KP2 + (size_t)(ch * 32) * TP;
    #pragma unroll
    for (int uf = 0; uf < 9; ++uf) {
        int ub = uh * 144 + uf * 16 + 4 * lk;
        float4 b4 = *reinterpret_cast<const float4*>(sbp + s * TP + ub);
        float bias[4] = { b4.x, b4.y, b4.z, b4.w };
        #pragma unroll
        for (int cf = 0; cf < 2; ++cf) {
            int c = cf * 16 + lrow;
            short4v pk;
            #pragma unroll
            for (int r = 0; r < 4; ++r)
                pk[r] = (ub + r < T_N) ? (short)f2bf(acc[uf][cf][r] + bias[r])
                                       : (short)0;
            *reinterpret_cast<short4v*>(xrow + (size_t)c * TP + ub) = pk;
        }
    }
    #undef K1_WSTAGE
    #undef K1_ELOAD
    #undef K1_EWRITE
    #undef K1_WAITN
}

// ---------------------------------------------------------------------------
// k2: part[kz,m,n] = sum_{k chunk} xb[m,k'] * eT[n,k']
// grid (16 m-tiles of 64, 16 kz), 256 thr, 4 waves N-split (48 n each).
// ---------------------------------------------------------------------------
__global__ __launch_bounds__(256) void k2_mfma(
    const u16* __restrict__ xb, const u16* __restrict__ eT,
    float* __restrict__ part)
{
    __shared__ __align__(16) u16 Ab[2][64 * 64];    // 8 KB each
    const int m0 = blockIdx.x * 64;
    const int kz = blockIdx.y;
    const int kbase = kz * KC2;
    const int tid = threadIdx.x;
    const int w = tid >> 6, lane = tid & 63;
    const int lrow = lane & 15, lk = lane >> 4;

    #define K2_STAGE(st, step)                                                 \
        _Pragma("unroll")                                                      \
        for (int p = 0; p < 2; ++p) {                                          \
            int l = tid + p * 256;                                             \
            int r_ = l >> 3, q_ = l & 7;                                       \
            gload16(xb + (size_t)(m0 + r_) * KP2 + kbase + (step) * 64 +       \
                        ((q_ ^ (r_ & 7)) << 3),                                \
                    &Ab[st][l * 8]);                                           \
        }
    #define K2_BLOAD(step, dst)                                                \
        _Pragma("unroll")                                                      \
        for (int ct = 0; ct < 3; ++ct)                                         \
            _Pragma("unroll")                                                  \
            for (int ki = 0; ki < 2; ++ki)                                     \
                dst[ct][ki] = *reinterpret_cast<const short8*>(                \
                    eT + (size_t)(48 * w + 16 * ct + lrow) * KP2 + kbase +     \
                    (step) * 64 + ki * 32 + 8 * lk);

    f32x4 acc[4][3] = {};
    short8 bf[3][2], bn[3][2];

    K2_STAGE(0, 0);
    K2_BLOAD(0, bf);
    __syncthreads();

    for (int step = 0; step < 18; ++step) {
        const int st = step & 1;
        if (step < 17) {
            K2_STAGE(st ^ 1, step + 1);
            K2_BLOAD(step + 1, bn);
        }
        #pragma unroll
        for (int ki = 0; ki < 2; ++ki)
            #pragma unroll
            for (int rt = 0; rt < 4; ++rt) {
                int m = 16 * rt + lrow;
                int chunk = m * 8 + ((4 * ki + lk) ^ (m & 7));
                short8 af = *reinterpret_cast<const short8*>(&Ab[st][chunk * 8]);
                #pragma unroll
                for (int ct = 0; ct < 3; ++ct)
                    acc[rt][ct] = MFMA16(af, bf[ct][ki], acc[rt][ct]);
            }
        __syncthreads();
        #pragma unroll
        for (int ct = 0; ct < 3; ++ct)
            #pragma unroll
            for (int ki = 0; ki < 2; ++ki) bf[ct][ki] = bn[ct][ki];
    }

    #pragma unroll
    for (int rt = 0; rt < 4; ++rt)
        #pragma unroll
        for (int ct = 0; ct < 3; ++ct) {
            int n = 48 * w + 16 * ct + lrow;
            #pragma unroll
            for (int r = 0; r < 4; ++r) {
                int m = m0 + 16 * rt + 4 * lk + r;
                part[((size_t)kz * B_N + m) * EMBP + n] = acc[rt][ct][r];
            }
        }
    #undef K2_STAGE
    #undef K2_BLOAD
}

// ---------------------------------------------------------------------------
// k3: hb[m,n] = bf16(enc_b[n] + sum_z part[z,m,n]); n>=184 -> 0
// ---------------------------------------------------------------------------
__global__ __launch_bounds__(256) void k3_reduce(
    const float* __restrict__ part, const float* __restrict__ enc_b,
    u16* __restrict__ hb)
{
    int idx = blockIdx.x * 256 + threadIdx.x;
    if (idx >= B_N * EMBP) return;
    int n = idx % EMBP;
    float s = 0.f;
    if (n < EMB_N) {
        s = enc_b[n];
        #pragma unroll
        for (int z = 0; z < KZ2; ++z)
            s += part[(size_t)z * B_N * EMBP + idx];
    }
    hb[idx] = f2bf(s);
}

// ---------------------------------------------------------------------------
// k4: h1 = hb @ W1 + b1 (K=192); g = bf16(gelu(h1))
// ---------------------------------------------------------------------------
__global__ __launch_bounds__(256) void k4_mfma(
    const u16* __restrict__ hb, const u16* __restrict__ w1t,
    const float* __restrict__ b1, float* __restrict__ h1, u16* __restrict__ g)
{
    __shared__ __align__(16) u16 Ab[64 * EMBP];
    __shared__ __align__(16) u16 Bb[64 * EMBP];
    const int m0 = blockIdx.x * 64, n0 = blockIdx.y * 64;
    const int tid = threadIdx.x;
    const int w = tid >> 6, lane = tid & 63;
    const int wr = w >> 1, wc = w & 1;
    const int lrow = lane & 15, lk = lane >> 4;

    #pragma unroll
    for (int i = 0; i < 6; ++i) {
        int L = tid + i * 256;
        int row = L / 24, qp = L % 24;
        int ql = qp ^ (row & 7);
        gload16(hb  + (size_t)(m0 + row) * EMBP + ql * 8, &Ab[(size_t)L * 8]);
        gload16(w1t + (size_t)(n0 + row) * EMBP + ql * 8, &Bb[(size_t)L * 8]);
    }
    __syncthreads();

    f32x4 acc[2][2] = {};
    #pragma unroll
    for (int ks = 0; ks < 6; ++ks) {
        #pragma unroll
        for (int rt = 0; rt < 2; ++rt) {
            int c = 32 * wr + 16 * rt + lrow;
            short8 af = *reinterpret_cast<const short8*>(
                &Ab[c * EMBP + (((4 * ks + lk) ^ (c & 7)) * 8)]);
            #pragma unroll
            for (int ct = 0; ct < 2; ++ct) {
                int nl = 32 * wc + 16 * ct + lrow;
                short8 bfv = *reinterpret_cast<const short8*>(
                    &Bb[nl * EMBP + (((4 * ks + lk) ^ (nl & 7)) * 8)]);
                acc[rt][ct] = MFMA16(af, bfv, acc[rt][ct]);
            }
        }
    }
    #pragma unroll
    for (int rt = 0; rt < 2; ++rt)
        #pragma unroll
        for (int ct = 0; ct < 2; ++ct) {
            int n = n0 + 32 * wc + 16 * ct + lrow;
            #pragma unroll
            for (int r = 0; r < 4; ++r) {
                int m = m0 + 32 * wr + 16 * rt + 4 * lk + r;
                float v = acc[rt][ct][r] + b1[n];
                size_t o = (size_t)m * PROJ_N + n;
                h1[o] = v;
                g[o] = f2bf(gelu_exact(v));
            }
        }
}

// ---------------------------------------------------------------------------
// k5: part2[kz] = g @ W2 chunk (K=512 each), BK=64, dbuf
// ---------------------------------------------------------------------------
__global__ __launch_bounds__(256) void k5_mfma(
    const u16* __restrict__ g, const u16* __restrict__ w2t,
    float* __restrict__ part2)
{
    __shared__ __align__(16) u16 Ab[2][64 * 64];
    __shared__ __align__(16) u16 Bb[2][64 * 64];
    const int m0 = blockIdx.x * 64, n0 = blockIdx.y * 64;
    const int kz = blockIdx.z;
    const int kbase = kz * (PROJ_N / KZ5);
    const int tid = threadIdx.x;
    const int w = tid >> 6, lane = tid & 63;
    const int wr = w >> 1, wc = w & 1;
    const int lrow = lane & 15, lk = lane >> 4;

    const int r0 = tid >> 3, q0 = tid & 7;
    const int r1 = (tid + 256) >> 3;
    const u16* a0 = g + (size_t)(m0 + r0) * PROJ_N + (q0 ^ (r0 & 7)) * 8;
    const u16* a1 = g + (size_t)(m0 + r1) * PROJ_N + (q0 ^ (r1 & 7)) * 8;
    const u16* b0 = w2t + (size_t)(n0 + r0) * PROJ_N + (q0 ^ (r0 & 7)) * 8;
    const u16* b1p = w2t + (size_t)(n0 + r1) * PROJ_N + (q0 ^ (r1 & 7)) * 8;

    f32x4 acc[2][2] = {};
    int buf = 0;
    gload16(a0 + kbase, &Ab[0][(size_t)(w * 64) * 8]);
    gload16(a1 + kbase, &Ab[0][(size_t)(w * 64 + 256) * 8]);
    gload16(b0 + kbase, &Bb[0][(size_t)(w * 64) * 8]);
    gload16(b1p + kbase, &Bb[0][(size_t)(w * 64 + 256) * 8]);
    __syncthreads();

    for (int step = 0; step < 8; ++step) {
        if (step < 7) {
            int k0 = kbase + (step + 1) * 64;
            gload16(a0 + k0, &Ab[buf ^ 1][(size_t)(w * 64) * 8]);
            gload16(a1 + k0, &Ab[buf ^ 1][(size_t)(w * 64 + 256) * 8]);
            gload16(b0 + k0, &Bb[buf ^ 1][(size_t)(w * 64) * 8]);
            gload16(b1p + k0, &Bb[buf ^ 1][(size_t)(w * 64 + 256) * 8]);
        }
        #pragma unroll
        for (int ki = 0; ki < 2; ++ki) {
            #pragma unroll
            for (int rt = 0; rt < 2; ++rt) {
                int c = 32 * wr + 16 * rt + lrow;
                short8 af = *reinterpret_cast<const short8*>(
                    &Ab[buf][c * 64 + (((lk + 4 * ki) ^ (c & 7)) * 8)]);
                #pragma unroll
                for (int ct = 0; ct < 2; ++ct) {
                    int nl = 32 * wc + 16 * ct + lrow;
                    short8 bfv = *reinterpret_cast<const short8*>(
                        &Bb[buf][nl * 64 + (((lk + 4 * ki) ^ (nl & 7)) * 8)]);
                    acc[rt][ct] = MFMA16(af, bfv, acc[rt][ct]);
                }
            }
        }
        __syncthreads();
        buf ^= 1;
    }
    #pragma unroll
    for (int rt = 0; rt < 2; ++rt)
        #pragma unroll
        for (int ct = 0; ct < 2; ++ct) {
            int n = n0 + 32 * wc + 16 * ct + lrow;
            #pragma unroll
            for (int r = 0; r < 4; ++r) {
                int m = m0 + 32 * wr + 16 * rt + 4 * lk + r;
                part2[(size_t)kz * B_N * PROJ_N + (size_t)m * PROJ_N + n] = acc[rt][ct][r];
            }
        }
}

// ---------------------------------------------------------------------------
// k5r_ln: hr = h1 + (part2[0]+part2[1]+b2); out = LN(hr)*gamma+beta
// ---------------------------------------------------------------------------
__global__ __launch_bounds__(256) void k5r_ln(
    const float* __restrict__ part2, const float* __restrict__ h1,
    const float* __restrict__ b2, const float* __restrict__ gamma,
    const float* __restrict__ beta, float* __restrict__ out)
{
    const int m = blockIdx.x;
    const int tid = threadIdx.x;
    const float4* h4 = reinterpret_cast<const float4*>(h1 + (size_t)m * PROJ_N);
    const float4* p0 = reinterpret_cast<const float4*>(part2 + (size_t)m * PROJ_N);
    const float4* p1 = reinterpret_cast<const float4*>(part2 + (size_t)(B_N + m) * PROJ_N);
    const float4* b4 = reinterpret_cast<const float4*>(b2);
    float4 va = h4[tid], vb = p0[tid], vc = p1[tid], vd = b4[tid];
    float v[4] = { va.x + vb.x + vc.x + vd.x, va.y + vb.y + vc.y + vd.y,
                   va.z + vb.z + vc.z + vd.z, va.w + vb.w + vc.w + vd.w };
    float s = 0.f, sq = 0.f;
    #pragma unroll
    for (int i = 0; i < 4; ++i) { s += v[i]; sq += v[i] * v[i]; }
    #pragma unroll
    for (int off = 32; off > 0; off >>= 1) {
        s  += __shfl_down(s, off);
        sq += __shfl_down(sq, off);
    }
    __shared__ float ss[4], ssq[4];
    int wid = tid >> 6, lane = tid & 63;
    if (lane == 0) { ss[wid] = s; ssq[wid] = sq; }
    __syncthreads();
    if (tid == 0) {
        float a = 0.f, bsum = 0.f;
        #pragma unroll
        for (int q = 0; q < 4; ++q) { a += ss[q]; bsum += ssq[q]; }
        ss[0] = a; ssq[0] = bsum;
    }
    __syncthreads();
    float mu  = ss[0] * (1.0f / PROJ_N);
    float var = ssq[0] * (1.0f / PROJ_N) - mu * mu;
    float rs  = rsqrtf(var + 1e-5f);
    const float4 g4 = reinterpret_cast<const float4*>(gamma)[tid];
    const float4 be4 = reinterpret_cast<const float4*>(beta)[tid];
    float gg[4] = { g4.x, g4.y, g4.z, g4.w };
    float bb[4] = { be4.x, be4.y, be4.z, be4.w };
    float4 o4;
    float* op = reinterpret_cast<float*>(&o4);
    #pragma unroll
    for (int i = 0; i < 4; ++i) op[i] = (v[i] - mu) * rs * gg[i] + bb[i];
    reinterpret_cast<float4*>(out + (size_t)m * PROJ_N)[tid] = o4;
}

// ---------------------------------------------------------------------------
extern "C" void kernel_launch(void* const* d_in, const int* in_sizes, int n_in,
                              void* d_out, int out_size, void* d_ws, size_t ws_size,
                              hipStream_t stream)
{
    const float* eeg    = (const float*)d_in[0];
    const int*   sid    = (const int*)  d_in[1];
    const float* subj_W = (const float*)d_in[2];
    const float* subj_b = (const float*)d_in[3];
    const float* enc_W  = (const float*)d_in[4];
    const float* enc_b  = (const float*)d_in[5];
    const float* W1     = (const float*)d_in[6];
    const float* b1     = (const float*)d_in[7];
    const float* W2     = (const float*)d_in[8];
    const float* b2     = (const float*)d_in[9];
    const float* gamma  = (const float*)d_in[10];
    const float* beta   = (const float*)d_in[11];
    float* out = (float*)d_out;

    char* w = (char*)d_ws;
    u16*   xb    = (u16*)(w);                    // 37,748,736 (1024*18432*2)
    u16*   Wb    = (u16*)(w + 37748736);         //  1,658,880 (10*288*288*2)
    u16*   eT    = (u16*)(w + 39407616);         //  7,077,888 (192*18432*2)
    u16*   w1t   = (u16*)(w + 46485504);         //    393,216
    u16*   w2t   = (u16*)(w + 46878720);         //  2,097,152
    u16*   hb    = (u16*)(w + 48975872);         //    393,216
    float* h1    = (float*)(w + 49369088);       //  4,194,304
    u16*   g     = (u16*)(w + 53563392);         //  2,097,152
    float* sbp   = (float*)(w + 55660544);       //     11,520 (10*288*4)
    int*   bsq   = (int*)(w + 55672064);         //      4,224
    float* part  = (float*)(w + 55676288);       // 12,582,912 (16*1024*192*4)
    float* part2 = (float*)(w + 68259200);       //  8,388,608 -> end 76,647,808

    p_all<<<dim3(SEC_N), 256, 0, stream>>>(sid, subj_W, enc_W, W1, W2, subj_b,
                                           Wb, eT, w1t, w2t, bsq, sbp);
    k1p  <<<dim3(GMAX, 2), 512, 0, stream>>>(eeg, sid, Wb, sbp, bsq, xb);
    k2_mfma<<<dim3(16, KZ2), 256, 0, stream>>>(xb, eT, part);
    k3_reduce<<<dim3((B_N * EMBP + 255) / 256), 256, 0, stream>>>(part, enc_b, hb);
    k4_mfma<<<dim3(16, 16), 256, 0, stream>>>(hb, w1t, b1, h1, g);
    k5_mfma<<<dim3(16, 16, KZ5), 256, 0, stream>>>(g, w2t, part2);
    k5r_ln <<<dim3(B_N), 256, 0, stream>>>(part2, h1, b2, gamma, beta, out);
}